// Round 17
// baseline (231.320 us; speedup 1.0000x reference)
//
#include <hip/hip_runtime.h>
#include <math.h>

// ---------------------------------------------------------------------------
// Decoder_82764019794508: LIIF-style decoder.
// R17: R16 post-mortem — crec (37.7MB) likely overflowed ws (~70MB total vs
// R15's proven ~38MB); bundled changes masked it. Keep only the safe change:
// scatter un-fused from conv3x3 (standalone 1024-thr kernel, 0.6KB LDS ->
// full occupancy; R15's fused_back gave scatter blocks the conv's 37.4KB
// LDS). Decoder/memory layout identical to R15 (bit-identical output).
// ---------------------------------------------------------------------------

#define HQ 384
#define HA 192
#define NQ (2 * HQ * HQ)   // 294912 queries
#define NBS (NQ / 1024)    // 288 sort blocks (1024 threads each)
#define NBKT 288           // 2 batches x 12x12 tiles of 16x16 px
#define NFLAT (NBKT * NBS) // 82944 = 81 * 1024

typedef _Float16 half8  __attribute__((ext_vector_type(8)));
typedef _Float16 half4v __attribute__((ext_vector_type(4)));
typedef float    float4v __attribute__((ext_vector_type(4)));

// bucket id from query coords: corner k=0 (vy=vx=-1) pixel, 16x16 tiles
__device__ __forceinline__ int bucket_id(int q, float cy, float cx) {
    const float LO = -1.0f + 1e-7f, HI = 1.0f - 1e-7f;
    const float RXY = 1.0f / (float)HA;
    float c0 = fminf(fmaxf((cy - RXY) + 1e-7f, LO), HI);
    float c1 = fminf(fmaxf((cx - RXY) + 1e-7f, LO), HI);
    int iy = (int)rintf(((c0 + 1.f) * (float)HA) * 0.5f - 0.5f);
    int ix = (int)rintf(((c1 + 1.f) * (float)HA) * 0.5f - 0.5f);
    iy = min(max(iy, 0), HA - 1);
    ix = min(max(ix, 0), HA - 1);
    int b = q / (HQ * HQ);
    return b * 144 + (iy >> 4) * 12 + (ix >> 4);
}

// ===========================================================================
// K1: fused_front — sort_count | prep frags | conv1x1 a4s/a32s | xcat z0
// ===========================================================================
__launch_bounds__(1024)
__global__ void fused_front(const float* __restrict__ coords,
                            int* __restrict__ cntT,
                            unsigned short* __restrict__ lrank,
                            const float* __restrict__ mw0,
                            const float* __restrict__ mw1,
                            const float* __restrict__ wf,
                            _Float16* __restrict__ fragTab,
                            _Float16* __restrict__ fragTabW,
                            const float* __restrict__ feats4,
                            const float* __restrict__ w4,
                            const float* __restrict__ b4,
                            const float* __restrict__ feats32,
                            const float* __restrict__ w32,
                            const float* __restrict__ b32,
                            float* __restrict__ a4s,
                            float* __restrict__ a32s,
                            const float* __restrict__ feats2,
                            const float* __restrict__ w2,
                            const float* __restrict__ b2,
                            _Float16* __restrict__ xcatH) {
    const int blk = blockIdx.x;
    const int tid = threadIdx.x;

    if (blk < 288) {
        __shared__ int lh[NBKT];
        if (tid < NBKT) lh[tid] = 0;
        __syncthreads();
        const int q = blk * 1024 + tid;
        float cy = coords[(size_t)q * 2 + 0];
        float cx = coords[(size_t)q * 2 + 1];
        int r = atomicAdd(&lh[bucket_id(q, cy, cx)], 1);
        lrank[q] = (unsigned short)r;
        __syncthreads();
        if (tid < NBKT) cntT[tid * NBS + blk] = lh[tid];
    } else if (blk < 300) {
        int t = (blk - 288) * 1024 + tid;
        if (t < 1536) {
            int f = t >> 6, L = t & 63;
            int n_ = L & 15, qd = L >> 4;
            _Float16 vals[8];
            if (f < 16) {
                int kc = f >> 2, nt = f & 3;
#pragma unroll
                for (int j = 0; j < 8; ++j) {
                    int kk = kc * 32 + qd * 8 + j;
                    vals[j] = (_Float16)((kk < 102) ? mw0[kk * 64 + nt * 16 + n_] : 0.f);
                }
            } else {
                int g = f - 16;
                int kc = g >> 2, nt = g & 3;
#pragma unroll
                for (int j = 0; j < 8; ++j) {
                    int kk = kc * 32 + qd * 8 + j;
                    vals[j] = (_Float16)mw1[kk * 64 + nt * 16 + n_];
                }
            }
#pragma unroll
            for (int j = 0; j < 8; ++j) fragTab[t * 8 + j] = vals[j];
        } else {
            int tw = t - 1536;
            if (tw < 27 * 6 * 64) {
                int s   = tw / 384;
                int rem = tw - s * 384;
                int nt  = rem >> 6;
                int L   = rem & 63;
                int n_  = L & 15, qd = L >> 4;
                int tap = s / 3, kc = s - tap * 3;
#pragma unroll
                for (int j = 0; j < 8; ++j) {
                    int kch = kc * 32 + qd * 8 + j;
                    fragTabW[tw * 8 + j] =
                        (_Float16)wf[(tap * 96 + kch) * 96 + nt * 16 + n_];
                }
            }
        }
    } else if (blk < 444) {
        int t = (blk - 300) * 1024 + tid;
        int p = t >> 3, cg = t & 7;
        const float4v* xr = (const float4v*)(feats4 + (size_t)p * 96);
        float4v acc = *(const float4v*)(b4 + cg * 4);
#pragma unroll
        for (int i4 = 0; i4 < 24; ++i4) {
            float4v xv = xr[i4];
            const float* wr = w4 + (i4 * 4) * 32 + cg * 4;
#pragma unroll
            for (int j = 0; j < 4; ++j) {
                float4v wv = *(const float4v*)(wr + j * 32);
                acc[0] = fmaf(xv[j], wv[0], acc[0]);
                acc[1] = fmaf(xv[j], wv[1], acc[1]);
                acc[2] = fmaf(xv[j], wv[2], acc[2]);
                acc[3] = fmaf(xv[j], wv[3], acc[3]);
            }
        }
        float4v o = {fmaxf(acc[0], 0.f), fmaxf(acc[1], 0.f),
                     fmaxf(acc[2], 0.f), fmaxf(acc[3], 0.f)};
        *(float4v*)(a4s + (size_t)p * 32 + cg * 4) = o;
    } else if (blk < 453) {
        int t = (blk - 444) * 1024 + tid;
        if (t >= 1152 * 8) return;
        int p = t >> 3, cg = t & 7;
        const float4v* xr = (const float4v*)(feats32 + (size_t)p * 160);
        float4v acc = *(const float4v*)(b32 + cg * 4);
#pragma unroll
        for (int i4 = 0; i4 < 40; ++i4) {
            float4v xv = xr[i4];
            const float* wr = w32 + (i4 * 4) * 32 + cg * 4;
#pragma unroll
            for (int j = 0; j < 4; ++j) {
                float4v wv = *(const float4v*)(wr + j * 32);
                acc[0] = fmaf(xv[j], wv[0], acc[0]);
                acc[1] = fmaf(xv[j], wv[1], acc[1]);
                acc[2] = fmaf(xv[j], wv[2], acc[2]);
                acc[3] = fmaf(xv[j], wv[3], acc[3]);
            }
        }
        float4v o = {fmaxf(acc[0], 0.f), fmaxf(acc[1], 0.f),
                     fmaxf(acc[2], 0.f), fmaxf(acc[3], 0.f)};
        *(float4v*)(a32s + (size_t)p * 32 + cg * 4) = o;
    } else {
        int t = (blk - 453) * 1024 + tid;
        int p = t >> 3, cg = t & 7;
        const float4v* xr = (const float4v*)(feats2 + (size_t)p * 64);
        float4v acc = *(const float4v*)(b2 + cg * 4);
#pragma unroll
        for (int i4 = 0; i4 < 16; ++i4) {
            float4v xv = xr[i4];
            const float* wr = w2 + (i4 * 4) * 32 + cg * 4;
#pragma unroll
            for (int j = 0; j < 4; ++j) {
                float4v wv = *(const float4v*)(wr + j * 32);
                acc[0] = fmaf(xv[j], wv[0], acc[0]);
                acc[1] = fmaf(xv[j], wv[1], acc[1]);
                acc[2] = fmaf(xv[j], wv[2], acc[2]);
                acc[3] = fmaf(xv[j], wv[3], acc[3]);
            }
        }
        half4v h;
        h[0] = (_Float16)fmaxf(acc[0], 0.f);
        h[1] = (_Float16)fmaxf(acc[1], 0.f);
        h[2] = (_Float16)fmaxf(acc[2], 0.f);
        h[3] = (_Float16)fmaxf(acc[3], 0.f);
        *(half4v*)(xcatH + (size_t)p * 96 + cg * 4) = h;
    }
}

// ===========================================================================
// K2: fused_mid — scan_chunks | upsample z1 | upsample z2
// ===========================================================================
__launch_bounds__(1024)
__global__ void fused_mid(const int* __restrict__ cntT,
                          int* __restrict__ scanEx,
                          int* __restrict__ chunkTot,
                          const float* __restrict__ a4s,
                          const float* __restrict__ a32s,
                          _Float16* __restrict__ xcatH) {
    const int blk = blockIdx.x;
    const int t = threadIdx.x;

    if (blk < 81) {
        __shared__ int s[1024];
        const int gi = blk * 1024 + t;
        int v = cntT[gi];
        s[t] = v;
        __syncthreads();
        for (int off = 1; off < 1024; off <<= 1) {
            int x = (t >= off) ? s[t - off] : 0;
            __syncthreads();
            s[t] += x;
            __syncthreads();
        }
        scanEx[gi] = s[t] - v;
        if (t == 1023) chunkTot[blk] = s[t];
        return;
    }

    const int z = (blk < 81 + 576) ? 1 : 2;
    int tt = ((z == 1) ? (blk - 81) : (blk - 657)) * 1024 + t;
    int p = tt >> 3, cg = tt & 7;

    const float* src = (z == 1) ? a4s : a32s;
    const int   S    = (z == 1) ? 96 : 24;
    const float inv  = (z == 1) ? 0.5f : 0.125f;
    const int   coff = (z == 1) ? 32 : 64;

    int x = p % HA;
    int r = p / HA;
    int y = r % HA;
    int b = r / HA;

    float u = ((float)y + 0.5f) * inv - 0.5f;
    float v = ((float)x + 0.5f) * inv - 0.5f;
    float fu = floorf(u), fv = floorf(v);
    float wu = u - fu, wv = v - fv;
    int y0 = (int)fu, x0 = (int)fv;
    int y1 = min(y0 + 1, S - 1);
    int x1 = min(x0 + 1, S - 1);
    y0 = max(y0, 0);
    x0 = max(x0, 0);

    const float* sb = src + (size_t)b * S * S * 32 + cg * 4;
    float4v v00 = *(const float4v*)(sb + (y0 * S + x0) * 32);
    float4v v01 = *(const float4v*)(sb + (y0 * S + x1) * 32);
    float4v v10 = *(const float4v*)(sb + (y1 * S + x0) * 32);
    float4v v11 = *(const float4v*)(sb + (y1 * S + x1) * 32);
    half4v h;
#pragma unroll
    for (int j = 0; j < 4; ++j) {
        float t0 = v00[j] * (1.f - wu) + v10[j] * wu;
        float t1 = v01[j] * (1.f - wu) + v11[j] * wu;
        h[j] = (_Float16)(t0 * (1.f - wv) + t1 * wv);
    }
    *(half4v*)(xcatH + (size_t)p * 96 + coff + cg * 4) = h;
}

// ===========================================================================
// K3: sort_scatter — standalone (1024 thr, 0.6KB LDS, inline 81-prefix)
// writes qidx/qdata exactly as R15's fused_back scatter section.
// ===========================================================================
__launch_bounds__(1024)
__global__ void sort_scatter(const float* __restrict__ coords,
                             const float* __restrict__ cells,
                             const int* __restrict__ scanEx,
                             const int* __restrict__ chunkTot,
                             const unsigned short* __restrict__ lrank,
                             int* __restrict__ qidx,
                             float4v* __restrict__ qdata) {
    __shared__ int pEx[128];
    const int tid = threadIdx.x;

    int v = 0;
    if (tid < 81) v = chunkTot[tid];
    if (tid < 128) pEx[tid] = v;
    __syncthreads();
    for (int off = 1; off < 128; off <<= 1) {
        int x = 0;
        if (tid < 128 && tid >= off) x = pEx[tid - off];
        __syncthreads();
        if (tid < 128) pEx[tid] += x;
        __syncthreads();
    }
    if (tid < 128) pEx[tid] -= v;   // inclusive -> exclusive
    __syncthreads();

    const int q = blockIdx.x * 1024 + tid;
    float cy = coords[(size_t)q * 2 + 0];
    float cx = coords[(size_t)q * 2 + 1];
    int bkt = bucket_id(q, cy, cx);
    int li  = bkt * NBS + blockIdx.x;
    int pos = pEx[li >> 10] + scanEx[li] + (int)lrank[q];
    qidx[pos] = q;
    float4v d = {cy, cx,
                 cells[(size_t)q * 2 + 0] * (float)HA,
                 cells[(size_t)q * 2 + 1] * (float)HA};
    qdata[pos] = d;
}

// ===========================================================================
// K4: conv3x3_mfma — standalone (576 blocks, 256 thr, 37.4KB LDS)
// ===========================================================================
__launch_bounds__(256, 4)
__global__ void conv3x3_mfma(const _Float16* __restrict__ xH,
                             const _Float16* __restrict__ fragTabW,
                             const float* __restrict__ bias,
                             _Float16* __restrict__ yH) {
    __shared__ _Float16 lds[10 * 18 * 104];
    const int blk = blockIdx.x;
    const int tid = threadIdx.x;
    const int lane = tid & 63;
    const int wv   = tid >> 6;
    const int n_   = lane & 15;
    const int qd   = lane >> 4;
    const int nh   = wv & 1;
    const int yg   = wv >> 1;
    const int bx0  = (blk % 12) * 16;
    const int by0  = ((blk / 12) % 24) * 8;
    const int b    = blk / 288;

    for (int idx = tid; idx < 2160; idx += 256) {
        int hy  = idx / 216;
        int rem = idx - hy * 216;
        int hx  = rem / 12;
        int cc  = rem - hx * 12;
        int gy = by0 + hy - 1, gx = bx0 + hx - 1;
        half8 v = {(_Float16)0.f, (_Float16)0.f, (_Float16)0.f, (_Float16)0.f,
                   (_Float16)0.f, (_Float16)0.f, (_Float16)0.f, (_Float16)0.f};
        if (gy >= 0 && gy < HA && gx >= 0 && gx < HA)
            v = *(const half8*)(xH + (((size_t)b * HA + gy) * HA + gx) * 96 + cc * 8);
        *(half8*)&lds[(hy * 18 + hx) * 104 + cc * 8] = v;
    }

    float bv[3];
#pragma unroll
    for (int j = 0; j < 3; ++j) bv[j] = bias[(nh * 3 + j) * 16 + n_];

    __syncthreads();

    float4v acc[4][3];
#pragma unroll
    for (int r = 0; r < 4; ++r)
#pragma unroll
        for (int j = 0; j < 3; ++j) {
            float4v z = {0.f, 0.f, 0.f, 0.f};
            acc[r][j] = z;
        }

#pragma unroll 1
    for (int ky = 0; ky < 3; ++ky)
#pragma unroll 1
        for (int kx = 0; kx < 3; ++kx) {
            const int tap = ky * 3 + kx;
#pragma unroll
            for (int kc = 0; kc < 3; ++kc) {
                const int s = tap * 3 + kc;
                half8 bf[3];
#pragma unroll
                for (int j = 0; j < 3; ++j)
                    bf[j] = *(const half8*)(fragTabW +
                            ((size_t)(s * 6 + nh * 3 + j) * 64 + lane) * 8);
#pragma unroll
                for (int r = 0; r < 4; ++r) {
                    const int yr = yg * 4 + r;
                    half8 a = *(const half8*)&lds[((yr + ky) * 18 + (n_ + kx)) * 104
                                                  + kc * 32 + qd * 8];
#pragma unroll
                    for (int j = 0; j < 3; ++j)
                        acc[r][j] = __builtin_amdgcn_mfma_f32_16x16x32_f16(
                            a, bf[j], acc[r][j], 0, 0, 0);
                }
            }
        }

#pragma unroll
    for (int r = 0; r < 4; ++r) {
        const int gy = by0 + yg * 4 + r;
#pragma unroll
        for (int j = 0; j < 3; ++j) {
            const int ch = (nh * 3 + j) * 16 + n_;
#pragma unroll
            for (int reg = 0; reg < 4; ++reg) {
                const int gx = bx0 + qd * 4 + reg;
                yH[(((size_t)b * HA + gy) * HA + gx) * 96 + ch] =
                    (_Float16)fmaxf(acc[r][j][reg] + bv[j], 0.f);
            }
        }
    }
}

// ===========================================================================
// K5: decoder — sorted gather + MLP, weight frags in LDS (R15, unchanged)
// ===========================================================================
__launch_bounds__(256, 4)
__global__ void decoder_mlp_mfma(const _Float16* __restrict__ asppH,
                                 const int* __restrict__ qidx,
                                 const float4v* __restrict__ qdata,
                                 const _Float16* __restrict__ fragTab,
                                 const float* __restrict__ mb0,
                                 const float* __restrict__ mb1,
                                 const float* __restrict__ mw2,
                                 const float* __restrict__ mb2,
                                 float* __restrict__ out) {
    __shared__ __align__(16) _Float16 fragL[24 * 64 * 8];  // 24576 B
    __shared__ _Float16 Hb[64 * 64];                       // 8192 B
    __shared__ float biasL[196];

    const int tid  = threadIdx.x;
    const int lane = tid & 63;
    const int wv   = tid >> 6;
    const int n_   = lane & 15;
    const int qd   = lane >> 4;
    const int r    = (blockIdx.x & 7) * 2304 + (blockIdx.x >> 3);
    const int m0   = wv * 16;

    // ---- per-lane corner data (issued before staging barrier) ----
    const int sp = r * 16 + (m0 >> 2) + (n_ >> 2);
    const float4v d = qdata[sp];
    const int   qq = qidx[sp];
    const int   b  = qq / (HQ * HQ);
    const float cy = d[0], cx = d[1], rcy = d[2], rcx = d[3];
    const int   k  = n_ & 3;

    const float LO = -1.0f + 1e-7f, HI = 1.0f - 1e-7f;
    const float RXY = 1.0f / (float)HA;
    const float vy = (k < 2) ? -1.f : 1.f;
    const float vx = (k & 1) ? 1.f : -1.f;

    float c0 = fminf(fmaxf((cy + vy * RXY) + 1e-7f, LO), HI);
    float c1 = fminf(fmaxf((cx + vx * RXY) + 1e-7f, LO), HI);
    int iy = (int)rintf(((c0 + 1.f) * (float)HA) * 0.5f - 0.5f);
    int ix = (int)rintf(((c1 + 1.f) * (float)HA) * 0.5f - 0.5f);
    iy = min(max(iy, 0), HA - 1);
    ix = min(max(ix, 0), HA - 1);

    const float cs0 = (((float)iy + 0.5f) / (float)HA) * 2.f - 1.f;
    const float cs1 = (((float)ix + 0.5f) / (float)HA) * 2.f - 1.f;
    const float r0 = (cy - cs0) * (float)HA;
    const float r1 = (cx - cs1) * (float)HA;
    const float area = fabsf(r0 * r1) + 1e-7f;
    const int   pix = ((b * HA + iy) * HA + ix) * 96;

    // ---- A fragments: kc=0..2 direct gather; kc=3 = extras in-register ----
    half8 A_[4];
    A_[0] = *(const half8*)(asppH + pix + 0 * 32 + qd * 8);
    A_[1] = *(const half8*)(asppH + pix + 1 * 32 + qd * 8);
    A_[2] = *(const half8*)(asppH + pix + 2 * 32 + qd * 8);
    {
        half8 e = {(_Float16)0.f, (_Float16)0.f, (_Float16)0.f, (_Float16)0.f,
                   (_Float16)0.f, (_Float16)0.f, (_Float16)0.f, (_Float16)0.f};
        if (qd == 0) {
            e[0] = (_Float16)r0;  e[1] = (_Float16)r1;
            e[2] = (_Float16)cy;  e[3] = (_Float16)cx;
            e[4] = (_Float16)rcy; e[5] = (_Float16)rcx;
        }
        A_[3] = e;
    }

    // ---- cooperative staging: fragTab -> fragL, biases ----
#pragma unroll
    for (int it = 0; it < 6; ++it) {
        const int i = it * 256 + tid;
        *(half8*)&fragL[i * 8] = *(const half8*)(fragTab + (size_t)i * 8);
    }
    if (tid < 64) {
        biasL[tid]       = mb0[tid];
        biasL[64 + tid]  = mb1[tid];
        biasL[128 + tid] = mw2[tid];
    }
    if (tid == 0) biasL[192] = mb2[0];
    __syncthreads();

    float mb0v[4], mb1v[4], w2v[4];
#pragma unroll
    for (int nt = 0; nt < 4; ++nt) {
        mb0v[nt] = biasL[nt * 16 + n_];
        mb1v[nt] = biasL[64 + nt * 16 + n_];
        w2v[nt]  = biasL[128 + nt * 16 + n_];
    }
    const float mb2s = biasL[192];

    // ---- layer0: 16 MFMAs ----
    float4v acc[4];
#pragma unroll
    for (int nt = 0; nt < 4; ++nt) {
        float4v t = {mb0v[nt], mb0v[nt], mb0v[nt], mb0v[nt]};
        acc[nt] = t;
    }
#pragma unroll
    for (int kc = 0; kc < 4; ++kc)
#pragma unroll
        for (int nt = 0; nt < 4; ++nt) {
            half8 b0 = *(const half8*)&fragL[((kc * 4 + nt) * 64 + lane) * 8];
            acc[nt] = __builtin_amdgcn_mfma_f32_16x16x32_f16(A_[kc], b0,
                                                             acc[nt], 0, 0, 0);
        }

    // ---- relu -> Hb (wave-local swizzled slice) ----
#pragma unroll
    for (int nt = 0; nt < 4; ++nt)
#pragma unroll
        for (int reg = 0; reg < 4; ++reg) {
            const int hr = m0 + qd * 4 + reg;
            const int nn = nt * 16 + n_;
            Hb[hr * 64 + (((nn >> 3) ^ (hr & 7)) * 8) + (nn & 7)] =
                (_Float16)fmaxf(acc[nt][reg], 0.f);
        }
    __builtin_amdgcn_s_waitcnt(0);   // drain LDS writes (wave-local dep)

    // ---- layer1: 8 MFMAs ----
    const int row = m0 + n_;
    float4v acc1[4];
#pragma unroll
    for (int nt = 0; nt < 4; ++nt) {
        float4v t = {mb1v[nt], mb1v[nt], mb1v[nt], mb1v[nt]};
        acc1[nt] = t;
    }
#pragma unroll
    for (int kc = 0; kc < 2; ++kc) {
        half8 a1 = *(const half8*)&Hb[row * 64 + (((kc * 4 + qd) ^ (row & 7)) * 8)];
#pragma unroll
        for (int nt = 0; nt < 4; ++nt) {
            half8 b1 = *(const half8*)&fragL[((16 + kc * 4 + nt) * 64 + lane) * 8];
            acc1[nt] = __builtin_amdgcn_mfma_f32_16x16x32_f16(a1, b1,
                                                              acc1[nt], 0, 0, 0);
        }
    }

    // ---- layer2 + in-wave combine ----
    float p[4];
#pragma unroll
    for (int reg = 0; reg < 4; ++reg) {
        float s = 0.f;
#pragma unroll
        for (int nt = 0; nt < 4; ++nt)
            s = fmaf(fmaxf(acc1[nt][reg], 0.f), w2v[nt], s);
        s += __shfl_xor(s, 1, 64);
        s += __shfl_xor(s, 2, 64);
        s += __shfl_xor(s, 4, 64);
        s += __shfl_xor(s, 8, 64);
        p[reg] = s + mb2s;
    }

    float a0s = __shfl(area, qd * 4 + 0, 64);
    float a1s = __shfl(area, qd * 4 + 1, 64);
    float a2s = __shfl(area, qd * 4 + 2, 64);
    float a3s = __shfl(area, qd * 4 + 3, 64);
    int   oq  = __shfl(qq,   qd * 4, 64);

    if (n_ == 0) {
        float num = p[0] * a3s + p[1] * a2s + p[2] * a1s + p[3] * a0s;
        float den = a0s + a1s + a2s + a3s;
        out[oq] = num / den;
    }
}

// ---------------------------------------------------------------------------
extern "C" void kernel_launch(void* const* d_in, const int* in_sizes, int n_in,
                              void* d_out, int out_size, void* d_ws, size_t ws_size,
                              hipStream_t stream) {
    (void)in_sizes; (void)n_in; (void)out_size; (void)ws_size;
    const float* feats2  = (const float*)d_in[0];
    const float* feats4  = (const float*)d_in[1];
    const float* feats32 = (const float*)d_in[2];
    const float* coords  = (const float*)d_in[3];
    const float* cells   = (const float*)d_in[4];
    const float* w2  = (const float*)d_in[5];
    const float* b2  = (const float*)d_in[6];
    const float* w4  = (const float*)d_in[7];
    const float* b4  = (const float*)d_in[8];
    const float* w32 = (const float*)d_in[9];
    const float* b32 = (const float*)d_in[10];
    const float* wf  = (const float*)d_in[11];
    const float* bf  = (const float*)d_in[12];
    const float* mw0 = (const float*)d_in[13];
    const float* mb0 = (const float*)d_in[14];
    const float* mw1 = (const float*)d_in[15];
    const float* mb1 = (const float*)d_in[16];
    const float* mw2 = (const float*)d_in[17];
    const float* mb2 = (const float*)d_in[18];

    float* ws = (float*)d_ws;
    float*    a4s   = ws;                          // 589824 f
    float*    a32s  = a4s + 589824;                // 36864 f
    _Float16* xcatH = (_Float16*)(a32s + 36864);   // 7,077,888 h
    _Float16* asppH = xcatH + 7077888;             // 7,077,888 h
    _Float16* fragTab  = asppH + 7077888;          // 12,288 h
    _Float16* fragTabW = fragTab + 12288;          // 82,944 h
    float4v*  qdata = (float4v*)(fragTabW + 82944);   // NQ * 16 B
    int*      qidx  = (int*)(qdata + NQ);             // NQ ints
    int*      cntT  = qidx + NQ;                      // NFLAT ints
    int*      scanEx = cntT + NFLAT;                  // NFLAT ints
    int*      chunkTot = scanEx + NFLAT;              // 81 ints (pad 128)
    unsigned short* lrank = (unsigned short*)(chunkTot + 128);  // NQ u16
    float* out = (float*)d_out;

    fused_front<<<1029, 1024, 0, stream>>>(coords, cntT, lrank,
                                           mw0, mw1, wf, fragTab, fragTabW,
                                           feats4, w4, b4, feats32, w32, b32,
                                           a4s, a32s, feats2, w2, b2, xcatH);
    fused_mid<<<1233, 1024, 0, stream>>>(cntT, scanEx, chunkTot,
                                         a4s, a32s, xcatH);
    sort_scatter<<<NBS, 1024, 0, stream>>>(coords, cells, scanEx, chunkTot,
                                           lrank, qidx, qdata);
    conv3x3_mfma<<<576, 256, 0, stream>>>(xcatH, fragTabW, bf, asppH);
    decoder_mlp_mfma<<<18432, 256, 0, stream>>>(asppH, qidx, qdata, fragTab,
                                                mb0, mb1, mw2, mb2, out);
}

// Round 18
// 215.460 us; speedup vs baseline: 1.0736x; 1.0736x over previous
//
#include <hip/hip_runtime.h>
#include <math.h>

// ---------------------------------------------------------------------------
// Decoder_82764019794508: LIIF-style decoder.
// R18: (1) revert to R15's 3-kernel structure (R17 falsified the scatter-
// throttle theory: un-fusing cost +6.6us). (2) decoder blocks x4: 1024 thr
// = 16 waves = 256 rows; fragL staging amortized 4x (was 453MB of L2 reads
// across 18432 blocks), LDS 58KB -> 2 blocks/CU = 32 waves/CU (HW max).
// launch_bounds(1024,8) caps VGPR at 64 (52 used). Row mapping preserved ->
// bit-identical output.
// ---------------------------------------------------------------------------

#define HQ 384
#define HA 192
#define NQ (2 * HQ * HQ)   // 294912 queries
#define NBS (NQ / 1024)    // 288 sort blocks (1024 threads each)
#define NBKT 288           // 2 batches x 12x12 tiles of 16x16 px
#define NFLAT (NBKT * NBS) // 82944 = 81 * 1024

typedef _Float16 half8  __attribute__((ext_vector_type(8)));
typedef _Float16 half4v __attribute__((ext_vector_type(4)));
typedef float    float4v __attribute__((ext_vector_type(4)));

// bucket id from query coords: corner k=0 (vy=vx=-1) pixel, 16x16 tiles
__device__ __forceinline__ int bucket_id(int q, float cy, float cx) {
    const float LO = -1.0f + 1e-7f, HI = 1.0f - 1e-7f;
    const float RXY = 1.0f / (float)HA;
    float c0 = fminf(fmaxf((cy - RXY) + 1e-7f, LO), HI);
    float c1 = fminf(fmaxf((cx - RXY) + 1e-7f, LO), HI);
    int iy = (int)rintf(((c0 + 1.f) * (float)HA) * 0.5f - 0.5f);
    int ix = (int)rintf(((c1 + 1.f) * (float)HA) * 0.5f - 0.5f);
    iy = min(max(iy, 0), HA - 1);
    ix = min(max(ix, 0), HA - 1);
    int b = q / (HQ * HQ);
    return b * 144 + (iy >> 4) * 12 + (ix >> 4);
}

// ===========================================================================
// K1: fused_front — sort_count | prep frags | conv1x1 a4s/a32s | xcat z0
// ===========================================================================
__launch_bounds__(1024)
__global__ void fused_front(const float* __restrict__ coords,
                            int* __restrict__ cntT,
                            unsigned short* __restrict__ lrank,
                            const float* __restrict__ mw0,
                            const float* __restrict__ mw1,
                            const float* __restrict__ wf,
                            _Float16* __restrict__ fragTab,
                            _Float16* __restrict__ fragTabW,
                            const float* __restrict__ feats4,
                            const float* __restrict__ w4,
                            const float* __restrict__ b4,
                            const float* __restrict__ feats32,
                            const float* __restrict__ w32,
                            const float* __restrict__ b32,
                            float* __restrict__ a4s,
                            float* __restrict__ a32s,
                            const float* __restrict__ feats2,
                            const float* __restrict__ w2,
                            const float* __restrict__ b2,
                            _Float16* __restrict__ xcatH) {
    const int blk = blockIdx.x;
    const int tid = threadIdx.x;

    if (blk < 288) {
        __shared__ int lh[NBKT];
        if (tid < NBKT) lh[tid] = 0;
        __syncthreads();
        const int q = blk * 1024 + tid;
        float cy = coords[(size_t)q * 2 + 0];
        float cx = coords[(size_t)q * 2 + 1];
        int r = atomicAdd(&lh[bucket_id(q, cy, cx)], 1);
        lrank[q] = (unsigned short)r;
        __syncthreads();
        if (tid < NBKT) cntT[tid * NBS + blk] = lh[tid];
    } else if (blk < 300) {
        int t = (blk - 288) * 1024 + tid;
        if (t < 1536) {
            int f = t >> 6, L = t & 63;
            int n_ = L & 15, qd = L >> 4;
            _Float16 vals[8];
            if (f < 16) {
                int kc = f >> 2, nt = f & 3;
#pragma unroll
                for (int j = 0; j < 8; ++j) {
                    int kk = kc * 32 + qd * 8 + j;
                    vals[j] = (_Float16)((kk < 102) ? mw0[kk * 64 + nt * 16 + n_] : 0.f);
                }
            } else {
                int g = f - 16;
                int kc = g >> 2, nt = g & 3;
#pragma unroll
                for (int j = 0; j < 8; ++j) {
                    int kk = kc * 32 + qd * 8 + j;
                    vals[j] = (_Float16)mw1[kk * 64 + nt * 16 + n_];
                }
            }
#pragma unroll
            for (int j = 0; j < 8; ++j) fragTab[t * 8 + j] = vals[j];
        } else {
            int tw = t - 1536;
            if (tw < 27 * 6 * 64) {
                int s   = tw / 384;
                int rem = tw - s * 384;
                int nt  = rem >> 6;
                int L   = rem & 63;
                int n_  = L & 15, qd = L >> 4;
                int tap = s / 3, kc = s - tap * 3;
#pragma unroll
                for (int j = 0; j < 8; ++j) {
                    int kch = kc * 32 + qd * 8 + j;
                    fragTabW[tw * 8 + j] =
                        (_Float16)wf[(tap * 96 + kch) * 96 + nt * 16 + n_];
                }
            }
        }
    } else if (blk < 444) {
        int t = (blk - 300) * 1024 + tid;
        int p = t >> 3, cg = t & 7;
        const float4v* xr = (const float4v*)(feats4 + (size_t)p * 96);
        float4v acc = *(const float4v*)(b4 + cg * 4);
#pragma unroll
        for (int i4 = 0; i4 < 24; ++i4) {
            float4v xv = xr[i4];
            const float* wr = w4 + (i4 * 4) * 32 + cg * 4;
#pragma unroll
            for (int j = 0; j < 4; ++j) {
                float4v wv = *(const float4v*)(wr + j * 32);
                acc[0] = fmaf(xv[j], wv[0], acc[0]);
                acc[1] = fmaf(xv[j], wv[1], acc[1]);
                acc[2] = fmaf(xv[j], wv[2], acc[2]);
                acc[3] = fmaf(xv[j], wv[3], acc[3]);
            }
        }
        float4v o = {fmaxf(acc[0], 0.f), fmaxf(acc[1], 0.f),
                     fmaxf(acc[2], 0.f), fmaxf(acc[3], 0.f)};
        *(float4v*)(a4s + (size_t)p * 32 + cg * 4) = o;
    } else if (blk < 453) {
        int t = (blk - 444) * 1024 + tid;
        if (t >= 1152 * 8) return;
        int p = t >> 3, cg = t & 7;
        const float4v* xr = (const float4v*)(feats32 + (size_t)p * 160);
        float4v acc = *(const float4v*)(b32 + cg * 4);
#pragma unroll
        for (int i4 = 0; i4 < 40; ++i4) {
            float4v xv = xr[i4];
            const float* wr = w32 + (i4 * 4) * 32 + cg * 4;
#pragma unroll
            for (int j = 0; j < 4; ++j) {
                float4v wv = *(const float4v*)(wr + j * 32);
                acc[0] = fmaf(xv[j], wv[0], acc[0]);
                acc[1] = fmaf(xv[j], wv[1], acc[1]);
                acc[2] = fmaf(xv[j], wv[2], acc[2]);
                acc[3] = fmaf(xv[j], wv[3], acc[3]);
            }
        }
        float4v o = {fmaxf(acc[0], 0.f), fmaxf(acc[1], 0.f),
                     fmaxf(acc[2], 0.f), fmaxf(acc[3], 0.f)};
        *(float4v*)(a32s + (size_t)p * 32 + cg * 4) = o;
    } else {
        int t = (blk - 453) * 1024 + tid;
        int p = t >> 3, cg = t & 7;
        const float4v* xr = (const float4v*)(feats2 + (size_t)p * 64);
        float4v acc = *(const float4v*)(b2 + cg * 4);
#pragma unroll
        for (int i4 = 0; i4 < 16; ++i4) {
            float4v xv = xr[i4];
            const float* wr = w2 + (i4 * 4) * 32 + cg * 4;
#pragma unroll
            for (int j = 0; j < 4; ++j) {
                float4v wv = *(const float4v*)(wr + j * 32);
                acc[0] = fmaf(xv[j], wv[0], acc[0]);
                acc[1] = fmaf(xv[j], wv[1], acc[1]);
                acc[2] = fmaf(xv[j], wv[2], acc[2]);
                acc[3] = fmaf(xv[j], wv[3], acc[3]);
            }
        }
        half4v h;
        h[0] = (_Float16)fmaxf(acc[0], 0.f);
        h[1] = (_Float16)fmaxf(acc[1], 0.f);
        h[2] = (_Float16)fmaxf(acc[2], 0.f);
        h[3] = (_Float16)fmaxf(acc[3], 0.f);
        *(half4v*)(xcatH + (size_t)p * 96 + cg * 4) = h;
    }
}

// ===========================================================================
// K2: fused_mid — scan_chunks | upsample z1 | upsample z2
// ===========================================================================
__launch_bounds__(1024)
__global__ void fused_mid(const int* __restrict__ cntT,
                          int* __restrict__ scanEx,
                          int* __restrict__ chunkTot,
                          const float* __restrict__ a4s,
                          const float* __restrict__ a32s,
                          _Float16* __restrict__ xcatH) {
    const int blk = blockIdx.x;
    const int t = threadIdx.x;

    if (blk < 81) {
        __shared__ int s[1024];
        const int gi = blk * 1024 + t;
        int v = cntT[gi];
        s[t] = v;
        __syncthreads();
        for (int off = 1; off < 1024; off <<= 1) {
            int x = (t >= off) ? s[t - off] : 0;
            __syncthreads();
            s[t] += x;
            __syncthreads();
        }
        scanEx[gi] = s[t] - v;
        if (t == 1023) chunkTot[blk] = s[t];
        return;
    }

    const int z = (blk < 81 + 576) ? 1 : 2;
    int tt = ((z == 1) ? (blk - 81) : (blk - 657)) * 1024 + t;
    int p = tt >> 3, cg = tt & 7;

    const float* src = (z == 1) ? a4s : a32s;
    const int   S    = (z == 1) ? 96 : 24;
    const float inv  = (z == 1) ? 0.5f : 0.125f;
    const int   coff = (z == 1) ? 32 : 64;

    int x = p % HA;
    int r = p / HA;
    int y = r % HA;
    int b = r / HA;

    float u = ((float)y + 0.5f) * inv - 0.5f;
    float v = ((float)x + 0.5f) * inv - 0.5f;
    float fu = floorf(u), fv = floorf(v);
    float wu = u - fu, wv = v - fv;
    int y0 = (int)fu, x0 = (int)fv;
    int y1 = min(y0 + 1, S - 1);
    int x1 = min(x0 + 1, S - 1);
    y0 = max(y0, 0);
    x0 = max(x0, 0);

    const float* sb = src + (size_t)b * S * S * 32 + cg * 4;
    float4v v00 = *(const float4v*)(sb + (y0 * S + x0) * 32);
    float4v v01 = *(const float4v*)(sb + (y0 * S + x1) * 32);
    float4v v10 = *(const float4v*)(sb + (y1 * S + x0) * 32);
    float4v v11 = *(const float4v*)(sb + (y1 * S + x1) * 32);
    half4v h;
#pragma unroll
    for (int j = 0; j < 4; ++j) {
        float t0 = v00[j] * (1.f - wu) + v10[j] * wu;
        float t1 = v01[j] * (1.f - wu) + v11[j] * wu;
        h[j] = (_Float16)(t0 * (1.f - wv) + t1 * wv);
    }
    *(half4v*)(xcatH + (size_t)p * 96 + coff + cg * 4) = h;
}

// ===========================================================================
// K3: fused_back — conv3x3_mfma | sort_scatter (R15 structure, proven)
// ===========================================================================
__launch_bounds__(256, 4)
__global__ void fused_back(const _Float16* __restrict__ xH,
                           const _Float16* __restrict__ fragTabW,
                           const float* __restrict__ bias,
                           _Float16* __restrict__ yH,
                           const float* __restrict__ coords,
                           const float* __restrict__ cells,
                           const int* __restrict__ scanEx,
                           const int* __restrict__ chunkTot,
                           const unsigned short* __restrict__ lrank,
                           int* __restrict__ qidx,
                           float4v* __restrict__ qdata) {
    __shared__ __align__(16) unsigned char smemU[37440];
    const int blk = blockIdx.x;
    const int tid = threadIdx.x;

    if (blk < 576) {
        _Float16* lds = (_Float16*)smemU;
        const int lane = tid & 63;
        const int wv   = tid >> 6;
        const int n_   = lane & 15;
        const int qd   = lane >> 4;
        const int nh   = wv & 1;
        const int yg   = wv >> 1;
        const int bx0  = (blk % 12) * 16;
        const int by0  = ((blk / 12) % 24) * 8;
        const int b    = blk / 288;

        for (int idx = tid; idx < 2160; idx += 256) {
            int hy  = idx / 216;
            int rem = idx - hy * 216;
            int hx  = rem / 12;
            int cc  = rem - hx * 12;
            int gy = by0 + hy - 1, gx = bx0 + hx - 1;
            half8 v = {(_Float16)0.f, (_Float16)0.f, (_Float16)0.f, (_Float16)0.f,
                       (_Float16)0.f, (_Float16)0.f, (_Float16)0.f, (_Float16)0.f};
            if (gy >= 0 && gy < HA && gx >= 0 && gx < HA)
                v = *(const half8*)(xH + (((size_t)b * HA + gy) * HA + gx) * 96 + cc * 8);
            *(half8*)&lds[(hy * 18 + hx) * 104 + cc * 8] = v;
        }

        float bv[3];
#pragma unroll
        for (int j = 0; j < 3; ++j) bv[j] = bias[(nh * 3 + j) * 16 + n_];

        __syncthreads();

        float4v acc[4][3];
#pragma unroll
        for (int r = 0; r < 4; ++r)
#pragma unroll
            for (int j = 0; j < 3; ++j) {
                float4v z = {0.f, 0.f, 0.f, 0.f};
                acc[r][j] = z;
            }

#pragma unroll 1
        for (int ky = 0; ky < 3; ++ky)
#pragma unroll 1
            for (int kx = 0; kx < 3; ++kx) {
                const int tap = ky * 3 + kx;
#pragma unroll
                for (int kc = 0; kc < 3; ++kc) {
                    const int s = tap * 3 + kc;
                    half8 bf[3];
#pragma unroll
                    for (int j = 0; j < 3; ++j)
                        bf[j] = *(const half8*)(fragTabW +
                                ((size_t)(s * 6 + nh * 3 + j) * 64 + lane) * 8);
#pragma unroll
                    for (int r = 0; r < 4; ++r) {
                        const int yr = yg * 4 + r;
                        half8 a = *(const half8*)&lds[((yr + ky) * 18 + (n_ + kx)) * 104
                                                      + kc * 32 + qd * 8];
#pragma unroll
                        for (int j = 0; j < 3; ++j)
                            acc[r][j] = __builtin_amdgcn_mfma_f32_16x16x32_f16(
                                a, bf[j], acc[r][j], 0, 0, 0);
                    }
                }
            }

#pragma unroll
        for (int r = 0; r < 4; ++r) {
            const int gy = by0 + yg * 4 + r;
#pragma unroll
            for (int j = 0; j < 3; ++j) {
                const int ch = (nh * 3 + j) * 16 + n_;
#pragma unroll
                for (int reg = 0; reg < 4; ++reg) {
                    const int gx = bx0 + qd * 4 + reg;
                    yH[(((size_t)b * HA + gy) * HA + gx) * 96 + ch] =
                        (_Float16)fmaxf(acc[r][j][reg] + bv[j], 0.f);
                }
            }
        }
    } else {
        int* pEx = (int*)smemU;   // 128 ints
        int v = 0;
        if (tid < 81) v = chunkTot[tid];
        if (tid < 128) pEx[tid] = v;
        __syncthreads();
        for (int off = 1; off < 128; off <<= 1) {
            int x = 0;
            if (tid < 128 && tid >= off) x = pEx[tid - off];
            __syncthreads();
            if (tid < 128) pEx[tid] += x;
            __syncthreads();
        }
        if (tid < 128) pEx[tid] -= v;   // inclusive -> exclusive
        __syncthreads();

        const int q = (blk - 576) * 256 + tid;
        float cy = coords[(size_t)q * 2 + 0];
        float cx = coords[(size_t)q * 2 + 1];
        int bkt = bucket_id(q, cy, cx);
        int sb  = q >> 10;
        int li  = bkt * NBS + sb;
        int pos = pEx[li >> 10] + scanEx[li] + (int)lrank[q];
        qidx[pos] = q;
        float4v d = {cy, cx,
                     cells[(size_t)q * 2 + 0] * (float)HA,
                     cells[(size_t)q * 2 + 1] * (float)HA};
        qdata[pos] = d;
    }
}

// ===========================================================================
// K4: decoder — 1024-thread blocks (16 waves = 256 rows), fragL staged
// once per 256 rows; LDS 58KB -> 2 blocks/CU = 32 waves/CU.
// ===========================================================================
__launch_bounds__(1024, 8)
__global__ void decoder_mlp_mfma(const _Float16* __restrict__ asppH,
                                 const int* __restrict__ qidx,
                                 const float4v* __restrict__ qdata,
                                 const _Float16* __restrict__ fragTab,
                                 const float* __restrict__ mb0,
                                 const float* __restrict__ mb1,
                                 const float* __restrict__ mw2,
                                 const float* __restrict__ mb2,
                                 float* __restrict__ out) {
    __shared__ __align__(16) _Float16 fragL[24 * 64 * 8];  // 24576 B
    __shared__ _Float16 Hb[256 * 64];                      // 32768 B
    __shared__ float biasL[196];

    const int tid  = threadIdx.x;
    const int lane = tid & 63;
    const int wv   = tid >> 6;            // 0..15
    const int n_   = lane & 15;
    const int qd   = lane >> 4;
    const int R    = (blockIdx.x & 7) * 576 + (blockIdx.x >> 3);
    const int m0   = wv * 16;             // row group within block (0..240)

    // ---- per-lane corner data (issued before staging barrier) ----
    const int sp = R * 64 + wv * 4 + (n_ >> 2);   // global query slot
    const float4v d = qdata[sp];
    const int   qq = qidx[sp];
    const int   b  = qq / (HQ * HQ);
    const float cy = d[0], cx = d[1], rcy = d[2], rcx = d[3];
    const int   k  = n_ & 3;

    const float LO = -1.0f + 1e-7f, HI = 1.0f - 1e-7f;
    const float RXY = 1.0f / (float)HA;
    const float vy = (k < 2) ? -1.f : 1.f;
    const float vx = (k & 1) ? 1.f : -1.f;

    float c0 = fminf(fmaxf((cy + vy * RXY) + 1e-7f, LO), HI);
    float c1 = fminf(fmaxf((cx + vx * RXY) + 1e-7f, LO), HI);
    int iy = (int)rintf(((c0 + 1.f) * (float)HA) * 0.5f - 0.5f);
    int ix = (int)rintf(((c1 + 1.f) * (float)HA) * 0.5f - 0.5f);
    iy = min(max(iy, 0), HA - 1);
    ix = min(max(ix, 0), HA - 1);

    const float cs0 = (((float)iy + 0.5f) / (float)HA) * 2.f - 1.f;
    const float cs1 = (((float)ix + 0.5f) / (float)HA) * 2.f - 1.f;
    const float r0 = (cy - cs0) * (float)HA;
    const float r1 = (cx - cs1) * (float)HA;
    const float area = fabsf(r0 * r1) + 1e-7f;
    const int   pix = ((b * HA + iy) * HA + ix) * 96;

    // ---- A fragments: kc=0..2 direct gather; kc=3 = extras in-register ----
    half8 A_[4];
    A_[0] = *(const half8*)(asppH + pix + 0 * 32 + qd * 8);
    A_[1] = *(const half8*)(asppH + pix + 1 * 32 + qd * 8);
    A_[2] = *(const half8*)(asppH + pix + 2 * 32 + qd * 8);
    {
        half8 e = {(_Float16)0.f, (_Float16)0.f, (_Float16)0.f, (_Float16)0.f,
                   (_Float16)0.f, (_Float16)0.f, (_Float16)0.f, (_Float16)0.f};
        if (qd == 0) {
            e[0] = (_Float16)r0;  e[1] = (_Float16)r1;
            e[2] = (_Float16)cy;  e[3] = (_Float16)cx;
            e[4] = (_Float16)rcy; e[5] = (_Float16)rcx;
        }
        A_[3] = e;
    }

    // ---- cooperative staging: fragTab -> fragL (1536 half8), biases ----
#pragma unroll
    for (int it = 0; it < 2; ++it) {
        const int i = it * 1024 + tid;
        if (i < 1536)
            *(half8*)&fragL[i * 8] = *(const half8*)(fragTab + (size_t)i * 8);
    }
    if (tid < 64) {
        biasL[tid]       = mb0[tid];
        biasL[64 + tid]  = mb1[tid];
        biasL[128 + tid] = mw2[tid];
    }
    if (tid == 0) biasL[192] = mb2[0];
    __syncthreads();

    float mb0v[4], mb1v[4], w2v[4];
#pragma unroll
    for (int nt = 0; nt < 4; ++nt) {
        mb0v[nt] = biasL[nt * 16 + n_];
        mb1v[nt] = biasL[64 + nt * 16 + n_];
        w2v[nt]  = biasL[128 + nt * 16 + n_];
    }
    const float mb2s = biasL[192];

    // ---- layer0: 16 MFMAs ----
    float4v acc[4];
#pragma unroll
    for (int nt = 0; nt < 4; ++nt) {
        float4v t = {mb0v[nt], mb0v[nt], mb0v[nt], mb0v[nt]};
        acc[nt] = t;
    }
#pragma unroll
    for (int kc = 0; kc < 4; ++kc)
#pragma unroll
        for (int nt = 0; nt < 4; ++nt) {
            half8 b0 = *(const half8*)&fragL[((kc * 4 + nt) * 64 + lane) * 8];
            acc[nt] = __builtin_amdgcn_mfma_f32_16x16x32_f16(A_[kc], b0,
                                                             acc[nt], 0, 0, 0);
        }

    // ---- relu -> Hb (wave-local 16-row slice, swizzled) ----
#pragma unroll
    for (int nt = 0; nt < 4; ++nt)
#pragma unroll
        for (int reg = 0; reg < 4; ++reg) {
            const int hr = m0 + qd * 4 + reg;
            const int nn = nt * 16 + n_;
            Hb[hr * 64 + (((nn >> 3) ^ (hr & 7)) * 8) + (nn & 7)] =
                (_Float16)fmaxf(acc[nt][reg], 0.f);
        }
    __builtin_amdgcn_s_waitcnt(0);   // drain LDS writes (wave-local dep)

    // ---- layer1: 8 MFMAs ----
    const int row = m0 + n_;
    float4v acc1[4];
#pragma unroll
    for (int nt = 0; nt < 4; ++nt) {
        float4v t = {mb1v[nt], mb1v[nt], mb1v[nt], mb1v[nt]};
        acc1[nt] = t;
    }
#pragma unroll
    for (int kc = 0; kc < 2; ++kc) {
        half8 a1 = *(const half8*)&Hb[row * 64 + (((kc * 4 + qd) ^ (row & 7)) * 8)];
#pragma unroll
        for (int nt = 0; nt < 4; ++nt) {
            half8 b1 = *(const half8*)&fragL[((16 + kc * 4 + nt) * 64 + lane) * 8];
            acc1[nt] = __builtin_amdgcn_mfma_f32_16x16x32_f16(a1, b1,
                                                              acc1[nt], 0, 0, 0);
        }
    }

    // ---- layer2 + in-wave combine ----
    float p[4];
#pragma unroll
    for (int reg = 0; reg < 4; ++reg) {
        float s = 0.f;
#pragma unroll
        for (int nt = 0; nt < 4; ++nt)
            s = fmaf(fmaxf(acc1[nt][reg], 0.f), w2v[nt], s);
        s += __shfl_xor(s, 1, 64);
        s += __shfl_xor(s, 2, 64);
        s += __shfl_xor(s, 4, 64);
        s += __shfl_xor(s, 8, 64);
        p[reg] = s + mb2s;
    }

    float a0s = __shfl(area, qd * 4 + 0, 64);
    float a1s = __shfl(area, qd * 4 + 1, 64);
    float a2s = __shfl(area, qd * 4 + 2, 64);
    float a3s = __shfl(area, qd * 4 + 3, 64);
    int   oq  = __shfl(qq,   qd * 4, 64);

    if (n_ == 0) {
        float num = p[0] * a3s + p[1] * a2s + p[2] * a1s + p[3] * a0s;
        float den = a0s + a1s + a2s + a3s;
        out[oq] = num / den;
    }
}

// ---------------------------------------------------------------------------
extern "C" void kernel_launch(void* const* d_in, const int* in_sizes, int n_in,
                              void* d_out, int out_size, void* d_ws, size_t ws_size,
                              hipStream_t stream) {
    (void)in_sizes; (void)n_in; (void)out_size; (void)ws_size;
    const float* feats2  = (const float*)d_in[0];
    const float* feats4  = (const float*)d_in[1];
    const float* feats32 = (const float*)d_in[2];
    const float* coords  = (const float*)d_in[3];
    const float* cells   = (const float*)d_in[4];
    const float* w2  = (const float*)d_in[5];
    const float* b2  = (const float*)d_in[6];
    const float* w4  = (const float*)d_in[7];
    const float* b4  = (const float*)d_in[8];
    const float* w32 = (const float*)d_in[9];
    const float* b32 = (const float*)d_in[10];
    const float* wf  = (const float*)d_in[11];
    const float* bf  = (const float*)d_in[12];
    const float* mw0 = (const float*)d_in[13];
    const float* mb0 = (const float*)d_in[14];
    const float* mw1 = (const float*)d_in[15];
    const float* mb1 = (const float*)d_in[16];
    const float* mw2 = (const float*)d_in[17];
    const float* mb2 = (const float*)d_in[18];

    float* ws = (float*)d_ws;
    float*    a4s   = ws;                          // 589824 f
    float*    a32s  = a4s + 589824;                // 36864 f
    _Float16* xcatH = (_Float16*)(a32s + 36864);   // 7,077,888 h
    _Float16* asppH = xcatH + 7077888;             // 7,077,888 h
    _Float16* fragTab  = asppH + 7077888;          // 12,288 h
    _Float16* fragTabW = fragTab + 12288;          // 82,944 h
    float4v*  qdata = (float4v*)(fragTabW + 82944);   // NQ * 16 B
    int*      qidx  = (int*)(qdata + NQ);             // NQ ints
    int*      cntT  = qidx + NQ;                      // NFLAT ints
    int*      scanEx = cntT + NFLAT;                  // NFLAT ints
    int*      chunkTot = scanEx + NFLAT;              // 81 ints (pad 128)
    unsigned short* lrank = (unsigned short*)(chunkTot + 128);  // NQ u16
    float* out = (float*)d_out;

    fused_front<<<1029, 1024, 0, stream>>>(coords, cntT, lrank,
                                           mw0, mw1, wf, fragTab, fragTabW,
                                           feats4, w4, b4, feats32, w32, b32,
                                           a4s, a32s, feats2, w2, b2, xcatH);
    fused_mid<<<1233, 1024, 0, stream>>>(cntT, scanEx, chunkTot,
                                         a4s, a32s, xcatH);
    fused_back<<<1728, 256, 0, stream>>>(xcatH, fragTabW, bf, asppH,
                                         coords, cells, scanEx, chunkTot,
                                         lrank, qidx, qdata);
    decoder_mlp_mfma<<<4608, 1024, 0, stream>>>(asppH, qidx, qdata, fragTab,
                                                mb0, mb1, mw2, mb2, out);
}

// Round 19
// 211.093 us; speedup vs baseline: 1.0958x; 1.0207x over previous
//
#include <hip/hip_runtime.h>
#include <math.h>

// ---------------------------------------------------------------------------
// Decoder_82764019794508: LIIF-style decoder.
// R19: decoder VALU diet. R18's 775 inst/wave (vs ~300 needed) is dominated
// by the Hb transpose store: 16 ds_write_u16 each with ~6-inst XOR-swizzle
// addressing. Replace with padded-stride layout Hb[row*72+col] (1-mad addr;
// writes ~2-way bank aliased = free per m136; layer1 read stays one
// contiguous ds_read_b128). LDS 62.2KB -> still 2 blocks/CU (32 waves).
// Bit-identical output. Front/mid/back = R18 verbatim.
// ---------------------------------------------------------------------------

#define HQ 384
#define HA 192
#define NQ (2 * HQ * HQ)   // 294912 queries
#define NBS (NQ / 1024)    // 288 sort blocks (1024 threads each)
#define NBKT 288           // 2 batches x 12x12 tiles of 16x16 px
#define NFLAT (NBKT * NBS) // 82944 = 81 * 1024
#define HBS 72             // Hb row stride in halves (64 + 8 pad)

typedef _Float16 half8  __attribute__((ext_vector_type(8)));
typedef _Float16 half4v __attribute__((ext_vector_type(4)));
typedef float    float4v __attribute__((ext_vector_type(4)));

// bucket id from query coords: corner k=0 (vy=vx=-1) pixel, 16x16 tiles
__device__ __forceinline__ int bucket_id(int q, float cy, float cx) {
    const float LO = -1.0f + 1e-7f, HI = 1.0f - 1e-7f;
    const float RXY = 1.0f / (float)HA;
    float c0 = fminf(fmaxf((cy - RXY) + 1e-7f, LO), HI);
    float c1 = fminf(fmaxf((cx - RXY) + 1e-7f, LO), HI);
    int iy = (int)rintf(((c0 + 1.f) * (float)HA) * 0.5f - 0.5f);
    int ix = (int)rintf(((c1 + 1.f) * (float)HA) * 0.5f - 0.5f);
    iy = min(max(iy, 0), HA - 1);
    ix = min(max(ix, 0), HA - 1);
    int b = q / (HQ * HQ);
    return b * 144 + (iy >> 4) * 12 + (ix >> 4);
}

// ===========================================================================
// K1: fused_front — sort_count | prep frags | conv1x1 a4s/a32s | xcat z0
// ===========================================================================
__launch_bounds__(1024)
__global__ void fused_front(const float* __restrict__ coords,
                            int* __restrict__ cntT,
                            unsigned short* __restrict__ lrank,
                            const float* __restrict__ mw0,
                            const float* __restrict__ mw1,
                            const float* __restrict__ wf,
                            _Float16* __restrict__ fragTab,
                            _Float16* __restrict__ fragTabW,
                            const float* __restrict__ feats4,
                            const float* __restrict__ w4,
                            const float* __restrict__ b4,
                            const float* __restrict__ feats32,
                            const float* __restrict__ w32,
                            const float* __restrict__ b32,
                            float* __restrict__ a4s,
                            float* __restrict__ a32s,
                            const float* __restrict__ feats2,
                            const float* __restrict__ w2,
                            const float* __restrict__ b2,
                            _Float16* __restrict__ xcatH) {
    const int blk = blockIdx.x;
    const int tid = threadIdx.x;

    if (blk < 288) {
        __shared__ int lh[NBKT];
        if (tid < NBKT) lh[tid] = 0;
        __syncthreads();
        const int q = blk * 1024 + tid;
        float cy = coords[(size_t)q * 2 + 0];
        float cx = coords[(size_t)q * 2 + 1];
        int r = atomicAdd(&lh[bucket_id(q, cy, cx)], 1);
        lrank[q] = (unsigned short)r;
        __syncthreads();
        if (tid < NBKT) cntT[tid * NBS + blk] = lh[tid];
    } else if (blk < 300) {
        int t = (blk - 288) * 1024 + tid;
        if (t < 1536) {
            int f = t >> 6, L = t & 63;
            int n_ = L & 15, qd = L >> 4;
            _Float16 vals[8];
            if (f < 16) {
                int kc = f >> 2, nt = f & 3;
#pragma unroll
                for (int j = 0; j < 8; ++j) {
                    int kk = kc * 32 + qd * 8 + j;
                    vals[j] = (_Float16)((kk < 102) ? mw0[kk * 64 + nt * 16 + n_] : 0.f);
                }
            } else {
                int g = f - 16;
                int kc = g >> 2, nt = g & 3;
#pragma unroll
                for (int j = 0; j < 8; ++j) {
                    int kk = kc * 32 + qd * 8 + j;
                    vals[j] = (_Float16)mw1[kk * 64 + nt * 16 + n_];
                }
            }
#pragma unroll
            for (int j = 0; j < 8; ++j) fragTab[t * 8 + j] = vals[j];
        } else {
            int tw = t - 1536;
            if (tw < 27 * 6 * 64) {
                int s   = tw / 384;
                int rem = tw - s * 384;
                int nt  = rem >> 6;
                int L   = rem & 63;
                int n_  = L & 15, qd = L >> 4;
                int tap = s / 3, kc = s - tap * 3;
#pragma unroll
                for (int j = 0; j < 8; ++j) {
                    int kch = kc * 32 + qd * 8 + j;
                    fragTabW[tw * 8 + j] =
                        (_Float16)wf[(tap * 96 + kch) * 96 + nt * 16 + n_];
                }
            }
        }
    } else if (blk < 444) {
        int t = (blk - 300) * 1024 + tid;
        int p = t >> 3, cg = t & 7;
        const float4v* xr = (const float4v*)(feats4 + (size_t)p * 96);
        float4v acc = *(const float4v*)(b4 + cg * 4);
#pragma unroll
        for (int i4 = 0; i4 < 24; ++i4) {
            float4v xv = xr[i4];
            const float* wr = w4 + (i4 * 4) * 32 + cg * 4;
#pragma unroll
            for (int j = 0; j < 4; ++j) {
                float4v wv = *(const float4v*)(wr + j * 32);
                acc[0] = fmaf(xv[j], wv[0], acc[0]);
                acc[1] = fmaf(xv[j], wv[1], acc[1]);
                acc[2] = fmaf(xv[j], wv[2], acc[2]);
                acc[3] = fmaf(xv[j], wv[3], acc[3]);
            }
        }
        float4v o = {fmaxf(acc[0], 0.f), fmaxf(acc[1], 0.f),
                     fmaxf(acc[2], 0.f), fmaxf(acc[3], 0.f)};
        *(float4v*)(a4s + (size_t)p * 32 + cg * 4) = o;
    } else if (blk < 453) {
        int t = (blk - 444) * 1024 + tid;
        if (t >= 1152 * 8) return;
        int p = t >> 3, cg = t & 7;
        const float4v* xr = (const float4v*)(feats32 + (size_t)p * 160);
        float4v acc = *(const float4v*)(b32 + cg * 4);
#pragma unroll
        for (int i4 = 0; i4 < 40; ++i4) {
            float4v xv = xr[i4];
            const float* wr = w32 + (i4 * 4) * 32 + cg * 4;
#pragma unroll
            for (int j = 0; j < 4; ++j) {
                float4v wv = *(const float4v*)(wr + j * 32);
                acc[0] = fmaf(xv[j], wv[0], acc[0]);
                acc[1] = fmaf(xv[j], wv[1], acc[1]);
                acc[2] = fmaf(xv[j], wv[2], acc[2]);
                acc[3] = fmaf(xv[j], wv[3], acc[3]);
            }
        }
        float4v o = {fmaxf(acc[0], 0.f), fmaxf(acc[1], 0.f),
                     fmaxf(acc[2], 0.f), fmaxf(acc[3], 0.f)};
        *(float4v*)(a32s + (size_t)p * 32 + cg * 4) = o;
    } else {
        int t = (blk - 453) * 1024 + tid;
        int p = t >> 3, cg = t & 7;
        const float4v* xr = (const float4v*)(feats2 + (size_t)p * 64);
        float4v acc = *(const float4v*)(b2 + cg * 4);
#pragma unroll
        for (int i4 = 0; i4 < 16; ++i4) {
            float4v xv = xr[i4];
            const float* wr = w2 + (i4 * 4) * 32 + cg * 4;
#pragma unroll
            for (int j = 0; j < 4; ++j) {
                float4v wv = *(const float4v*)(wr + j * 32);
                acc[0] = fmaf(xv[j], wv[0], acc[0]);
                acc[1] = fmaf(xv[j], wv[1], acc[1]);
                acc[2] = fmaf(xv[j], wv[2], acc[2]);
                acc[3] = fmaf(xv[j], wv[3], acc[3]);
            }
        }
        half4v h;
        h[0] = (_Float16)fmaxf(acc[0], 0.f);
        h[1] = (_Float16)fmaxf(acc[1], 0.f);
        h[2] = (_Float16)fmaxf(acc[2], 0.f);
        h[3] = (_Float16)fmaxf(acc[3], 0.f);
        *(half4v*)(xcatH + (size_t)p * 96 + cg * 4) = h;
    }
}

// ===========================================================================
// K2: fused_mid — scan_chunks | upsample z1 | upsample z2
// ===========================================================================
__launch_bounds__(1024)
__global__ void fused_mid(const int* __restrict__ cntT,
                          int* __restrict__ scanEx,
                          int* __restrict__ chunkTot,
                          const float* __restrict__ a4s,
                          const float* __restrict__ a32s,
                          _Float16* __restrict__ xcatH) {
    const int blk = blockIdx.x;
    const int t = threadIdx.x;

    if (blk < 81) {
        __shared__ int s[1024];
        const int gi = blk * 1024 + t;
        int v = cntT[gi];
        s[t] = v;
        __syncthreads();
        for (int off = 1; off < 1024; off <<= 1) {
            int x = (t >= off) ? s[t - off] : 0;
            __syncthreads();
            s[t] += x;
            __syncthreads();
        }
        scanEx[gi] = s[t] - v;
        if (t == 1023) chunkTot[blk] = s[t];
        return;
    }

    const int z = (blk < 81 + 576) ? 1 : 2;
    int tt = ((z == 1) ? (blk - 81) : (blk - 657)) * 1024 + t;
    int p = tt >> 3, cg = tt & 7;

    const float* src = (z == 1) ? a4s : a32s;
    const int   S    = (z == 1) ? 96 : 24;
    const float inv  = (z == 1) ? 0.5f : 0.125f;
    const int   coff = (z == 1) ? 32 : 64;

    int x = p % HA;
    int r = p / HA;
    int y = r % HA;
    int b = r / HA;

    float u = ((float)y + 0.5f) * inv - 0.5f;
    float v = ((float)x + 0.5f) * inv - 0.5f;
    float fu = floorf(u), fv = floorf(v);
    float wu = u - fu, wv = v - fv;
    int y0 = (int)fu, x0 = (int)fv;
    int y1 = min(y0 + 1, S - 1);
    int x1 = min(x0 + 1, S - 1);
    y0 = max(y0, 0);
    x0 = max(x0, 0);

    const float* sb = src + (size_t)b * S * S * 32 + cg * 4;
    float4v v00 = *(const float4v*)(sb + (y0 * S + x0) * 32);
    float4v v01 = *(const float4v*)(sb + (y0 * S + x1) * 32);
    float4v v10 = *(const float4v*)(sb + (y1 * S + x0) * 32);
    float4v v11 = *(const float4v*)(sb + (y1 * S + x1) * 32);
    half4v h;
#pragma unroll
    for (int j = 0; j < 4; ++j) {
        float t0 = v00[j] * (1.f - wu) + v10[j] * wu;
        float t1 = v01[j] * (1.f - wu) + v11[j] * wu;
        h[j] = (_Float16)(t0 * (1.f - wv) + t1 * wv);
    }
    *(half4v*)(xcatH + (size_t)p * 96 + coff + cg * 4) = h;
}

// ===========================================================================
// K3: fused_back — conv3x3_mfma | sort_scatter (R15 structure, proven)
// ===========================================================================
__launch_bounds__(256, 4)
__global__ void fused_back(const _Float16* __restrict__ xH,
                           const _Float16* __restrict__ fragTabW,
                           const float* __restrict__ bias,
                           _Float16* __restrict__ yH,
                           const float* __restrict__ coords,
                           const float* __restrict__ cells,
                           const int* __restrict__ scanEx,
                           const int* __restrict__ chunkTot,
                           const unsigned short* __restrict__ lrank,
                           int* __restrict__ qidx,
                           float4v* __restrict__ qdata) {
    __shared__ __align__(16) unsigned char smemU[37440];
    const int blk = blockIdx.x;
    const int tid = threadIdx.x;

    if (blk < 576) {
        _Float16* lds = (_Float16*)smemU;
        const int lane = tid & 63;
        const int wv   = tid >> 6;
        const int n_   = lane & 15;
        const int qd   = lane >> 4;
        const int nh   = wv & 1;
        const int yg   = wv >> 1;
        const int bx0  = (blk % 12) * 16;
        const int by0  = ((blk / 12) % 24) * 8;
        const int b    = blk / 288;

        for (int idx = tid; idx < 2160; idx += 256) {
            int hy  = idx / 216;
            int rem = idx - hy * 216;
            int hx  = rem / 12;
            int cc  = rem - hx * 12;
            int gy = by0 + hy - 1, gx = bx0 + hx - 1;
            half8 v = {(_Float16)0.f, (_Float16)0.f, (_Float16)0.f, (_Float16)0.f,
                       (_Float16)0.f, (_Float16)0.f, (_Float16)0.f, (_Float16)0.f};
            if (gy >= 0 && gy < HA && gx >= 0 && gx < HA)
                v = *(const half8*)(xH + (((size_t)b * HA + gy) * HA + gx) * 96 + cc * 8);
            *(half8*)&lds[(hy * 18 + hx) * 104 + cc * 8] = v;
        }

        float bv[3];
#pragma unroll
        for (int j = 0; j < 3; ++j) bv[j] = bias[(nh * 3 + j) * 16 + n_];

        __syncthreads();

        float4v acc[4][3];
#pragma unroll
        for (int r = 0; r < 4; ++r)
#pragma unroll
            for (int j = 0; j < 3; ++j) {
                float4v z = {0.f, 0.f, 0.f, 0.f};
                acc[r][j] = z;
            }

#pragma unroll 1
        for (int ky = 0; ky < 3; ++ky)
#pragma unroll 1
            for (int kx = 0; kx < 3; ++kx) {
                const int tap = ky * 3 + kx;
#pragma unroll
                for (int kc = 0; kc < 3; ++kc) {
                    const int s = tap * 3 + kc;
                    half8 bf[3];
#pragma unroll
                    for (int j = 0; j < 3; ++j)
                        bf[j] = *(const half8*)(fragTabW +
                                ((size_t)(s * 6 + nh * 3 + j) * 64 + lane) * 8);
#pragma unroll
                    for (int r = 0; r < 4; ++r) {
                        const int yr = yg * 4 + r;
                        half8 a = *(const half8*)&lds[((yr + ky) * 18 + (n_ + kx)) * 104
                                                      + kc * 32 + qd * 8];
#pragma unroll
                        for (int j = 0; j < 3; ++j)
                            acc[r][j] = __builtin_amdgcn_mfma_f32_16x16x32_f16(
                                a, bf[j], acc[r][j], 0, 0, 0);
                    }
                }
            }

#pragma unroll
        for (int r = 0; r < 4; ++r) {
            const int gy = by0 + yg * 4 + r;
#pragma unroll
            for (int j = 0; j < 3; ++j) {
                const int ch = (nh * 3 + j) * 16 + n_;
#pragma unroll
                for (int reg = 0; reg < 4; ++reg) {
                    const int gx = bx0 + qd * 4 + reg;
                    yH[(((size_t)b * HA + gy) * HA + gx) * 96 + ch] =
                        (_Float16)fmaxf(acc[r][j][reg] + bv[j], 0.f);
                }
            }
        }
    } else {
        int* pEx = (int*)smemU;   // 128 ints
        int v = 0;
        if (tid < 81) v = chunkTot[tid];
        if (tid < 128) pEx[tid] = v;
        __syncthreads();
        for (int off = 1; off < 128; off <<= 1) {
            int x = 0;
            if (tid < 128 && tid >= off) x = pEx[tid - off];
            __syncthreads();
            if (tid < 128) pEx[tid] += x;
            __syncthreads();
        }
        if (tid < 128) pEx[tid] -= v;   // inclusive -> exclusive
        __syncthreads();

        const int q = (blk - 576) * 256 + tid;
        float cy = coords[(size_t)q * 2 + 0];
        float cx = coords[(size_t)q * 2 + 1];
        int bkt = bucket_id(q, cy, cx);
        int sb  = q >> 10;
        int li  = bkt * NBS + sb;
        int pos = pEx[li >> 10] + scanEx[li] + (int)lrank[q];
        qidx[pos] = q;
        float4v d = {cy, cx,
                     cells[(size_t)q * 2 + 0] * (float)HA,
                     cells[(size_t)q * 2 + 1] * (float)HA};
        qdata[pos] = d;
    }
}

// ===========================================================================
// K4: decoder — 1024-thread blocks; Hb in padded-stride layout (no swizzle)
// LDS: fragL 24.6KB + Hb 36.9KB + bias 0.8KB = 62.2KB -> 2 blocks/CU.
// ===========================================================================
__launch_bounds__(1024, 8)
__global__ void decoder_mlp_mfma(const _Float16* __restrict__ asppH,
                                 const int* __restrict__ qidx,
                                 const float4v* __restrict__ qdata,
                                 const _Float16* __restrict__ fragTab,
                                 const float* __restrict__ mb0,
                                 const float* __restrict__ mb1,
                                 const float* __restrict__ mw2,
                                 const float* __restrict__ mb2,
                                 float* __restrict__ out) {
    __shared__ __align__(16) _Float16 fragL[24 * 64 * 8];  // 24576 B
    __shared__ __align__(16) _Float16 Hb[256 * HBS];       // 36864 B
    __shared__ float biasL[196];

    const int tid  = threadIdx.x;
    const int lane = tid & 63;
    const int wv   = tid >> 6;            // 0..15
    const int n_   = lane & 15;
    const int qd   = lane >> 4;
    const int R    = (blockIdx.x & 7) * 576 + (blockIdx.x >> 3);
    const int m0   = wv * 16;             // row group within block (0..240)

    // ---- per-lane corner data (issued before staging barrier) ----
    const int sp = R * 64 + wv * 4 + (n_ >> 2);   // global query slot
    const float4v d = qdata[sp];
    const int   qq = qidx[sp];
    const int   b  = qq / (HQ * HQ);
    const float cy = d[0], cx = d[1], rcy = d[2], rcx = d[3];
    const int   k  = n_ & 3;

    const float LO = -1.0f + 1e-7f, HI = 1.0f - 1e-7f;
    const float RXY = 1.0f / (float)HA;
    const float vy = (k < 2) ? -1.f : 1.f;
    const float vx = (k & 1) ? 1.f : -1.f;

    float c0 = fminf(fmaxf((cy + vy * RXY) + 1e-7f, LO), HI);
    float c1 = fminf(fmaxf((cx + vx * RXY) + 1e-7f, LO), HI);
    int iy = (int)rintf(((c0 + 1.f) * (float)HA) * 0.5f - 0.5f);
    int ix = (int)rintf(((c1 + 1.f) * (float)HA) * 0.5f - 0.5f);
    iy = min(max(iy, 0), HA - 1);
    ix = min(max(ix, 0), HA - 1);

    const float cs0 = (((float)iy + 0.5f) / (float)HA) * 2.f - 1.f;
    const float cs1 = (((float)ix + 0.5f) / (float)HA) * 2.f - 1.f;
    const float r0 = (cy - cs0) * (float)HA;
    const float r1 = (cx - cs1) * (float)HA;
    const float area = fabsf(r0 * r1) + 1e-7f;
    const int   pix = ((b * HA + iy) * HA + ix) * 96;

    // ---- A fragments: kc=0..2 direct gather; kc=3 = extras in-register ----
    half8 A_[4];
    A_[0] = *(const half8*)(asppH + pix + 0 * 32 + qd * 8);
    A_[1] = *(const half8*)(asppH + pix + 1 * 32 + qd * 8);
    A_[2] = *(const half8*)(asppH + pix + 2 * 32 + qd * 8);
    {
        half8 e = {(_Float16)0.f, (_Float16)0.f, (_Float16)0.f, (_Float16)0.f,
                   (_Float16)0.f, (_Float16)0.f, (_Float16)0.f, (_Float16)0.f};
        if (qd == 0) {
            e[0] = (_Float16)r0;  e[1] = (_Float16)r1;
            e[2] = (_Float16)cy;  e[3] = (_Float16)cx;
            e[4] = (_Float16)rcy; e[5] = (_Float16)rcx;
        }
        A_[3] = e;
    }

    // ---- cooperative staging: fragTab -> fragL (1536 half8), biases ----
#pragma unroll
    for (int it = 0; it < 2; ++it) {
        const int i = it * 1024 + tid;
        if (i < 1536)
            *(half8*)&fragL[i * 8] = *(const half8*)(fragTab + (size_t)i * 8);
    }
    if (tid < 64) {
        biasL[tid]       = mb0[tid];
        biasL[64 + tid]  = mb1[tid];
        biasL[128 + tid] = mw2[tid];
    }
    if (tid == 0) biasL[192] = mb2[0];
    __syncthreads();

    float mb0v[4], mb1v[4], w2v[4];
#pragma unroll
    for (int nt = 0; nt < 4; ++nt) {
        mb0v[nt] = biasL[nt * 16 + n_];
        mb1v[nt] = biasL[64 + nt * 16 + n_];
        w2v[nt]  = biasL[128 + nt * 16 + n_];
    }
    const float mb2s = biasL[192];

    // ---- layer0: 16 MFMAs ----
    float4v acc[4];
#pragma unroll
    for (int nt = 0; nt < 4; ++nt) {
        float4v t = {mb0v[nt], mb0v[nt], mb0v[nt], mb0v[nt]};
        acc[nt] = t;
    }
#pragma unroll
    for (int kc = 0; kc < 4; ++kc)
#pragma unroll
        for (int nt = 0; nt < 4; ++nt) {
            half8 b0 = *(const half8*)&fragL[((kc * 4 + nt) * 64 + lane) * 8];
            acc[nt] = __builtin_amdgcn_mfma_f32_16x16x32_f16(A_[kc], b0,
                                                             acc[nt], 0, 0, 0);
        }

    // ---- relu -> Hb (padded-stride layout: Hb[row*HBS + col]) ----
    {
        _Float16* hbase = &Hb[(m0 + qd * 4) * HBS + n_];
#pragma unroll
        for (int reg = 0; reg < 4; ++reg) {
            _Float16* hrow = hbase + reg * HBS;
#pragma unroll
            for (int nt = 0; nt < 4; ++nt)
                hrow[nt * 16] = (_Float16)fmaxf(acc[nt][reg], 0.f);
        }
    }
    __builtin_amdgcn_s_waitcnt(0);   // drain LDS writes (wave-local dep)

    // ---- layer1: 8 MFMAs ----
    const int row = m0 + n_;
    float4v acc1[4];
#pragma unroll
    for (int nt = 0; nt < 4; ++nt) {
        float4v t = {mb1v[nt], mb1v[nt], mb1v[nt], mb1v[nt]};
        acc1[nt] = t;
    }
#pragma unroll
    for (int kc = 0; kc < 2; ++kc) {
        half8 a1 = *(const half8*)&Hb[row * HBS + kc * 32 + qd * 8];
#pragma unroll
        for (int nt = 0; nt < 4; ++nt) {
            half8 b1 = *(const half8*)&fragL[((16 + kc * 4 + nt) * 64 + lane) * 8];
            acc1[nt] = __builtin_amdgcn_mfma_f32_16x16x32_f16(a1, b1,
                                                              acc1[nt], 0, 0, 0);
        }
    }

    // ---- layer2 + in-wave combine ----
    float p[4];
#pragma unroll
    for (int reg = 0; reg < 4; ++reg) {
        float s = 0.f;
#pragma unroll
        for (int nt = 0; nt < 4; ++nt)
            s = fmaf(fmaxf(acc1[nt][reg], 0.f), w2v[nt], s);
        s += __shfl_xor(s, 1, 64);
        s += __shfl_xor(s, 2, 64);
        s += __shfl_xor(s, 4, 64);
        s += __shfl_xor(s, 8, 64);
        p[reg] = s + mb2s;
    }

    float a0s = __shfl(area, qd * 4 + 0, 64);
    float a1s = __shfl(area, qd * 4 + 1, 64);
    float a2s = __shfl(area, qd * 4 + 2, 64);
    float a3s = __shfl(area, qd * 4 + 3, 64);
    int   oq  = __shfl(qq,   qd * 4, 64);

    if (n_ == 0) {
        float num = p[0] * a3s + p[1] * a2s + p[2] * a1s + p[3] * a0s;
        float den = a0s + a1s + a2s + a3s;
        out[oq] = num / den;
    }
}

// ---------------------------------------------------------------------------
extern "C" void kernel_launch(void* const* d_in, const int* in_sizes, int n_in,
                              void* d_out, int out_size, void* d_ws, size_t ws_size,
                              hipStream_t stream) {
    (void)in_sizes; (void)n_in; (void)out_size; (void)ws_size;
    const float* feats2  = (const float*)d_in[0];
    const float* feats4  = (const float*)d_in[1];
    const float* feats32 = (const float*)d_in[2];
    const float* coords  = (const float*)d_in[3];
    const float* cells   = (const float*)d_in[4];
    const float* w2  = (const float*)d_in[5];
    const float* b2  = (const float*)d_in[6];
    const float* w4  = (const float*)d_in[7];
    const float* b4  = (const float*)d_in[8];
    const float* w32 = (const float*)d_in[9];
    const float* b32 = (const float*)d_in[10];
    const float* wf  = (const float*)d_in[11];
    const float* bf  = (const float*)d_in[12];
    const float* mw0 = (const float*)d_in[13];
    const float* mb0 = (const float*)d_in[14];
    const float* mw1 = (const float*)d_in[15];
    const float* mb1 = (const float*)d_in[16];
    const float* mw2 = (const float*)d_in[17];
    const float* mb2 = (const float*)d_in[18];

    float* ws = (float*)d_ws;
    float*    a4s   = ws;                          // 589824 f
    float*    a32s  = a4s + 589824;                // 36864 f
    _Float16* xcatH = (_Float16*)(a32s + 36864);   // 7,077,888 h
    _Float16* asppH = xcatH + 7077888;             // 7,077,888 h
    _Float16* fragTab  = asppH + 7077888;          // 12,288 h
    _Float16* fragTabW = fragTab + 12288;          // 82,944 h
    float4v*  qdata = (float4v*)(fragTabW + 82944);   // NQ * 16 B
    int*      qidx  = (int*)(qdata + NQ);             // NQ ints
    int*      cntT  = qidx + NQ;                      // NFLAT ints
    int*      scanEx = cntT + NFLAT;                  // NFLAT ints
    int*      chunkTot = scanEx + NFLAT;              // 81 ints (pad 128)
    unsigned short* lrank = (unsigned short*)(chunkTot + 128);  // NQ u16
    float* out = (float*)d_out;

    fused_front<<<1029, 1024, 0, stream>>>(coords, cntT, lrank,
                                           mw0, mw1, wf, fragTab, fragTabW,
                                           feats4, w4, b4, feats32, w32, b32,
                                           a4s, a32s, feats2, w2, b2, xcatH);
    fused_mid<<<1233, 1024, 0, stream>>>(cntT, scanEx, chunkTot,
                                         a4s, a32s, xcatH);
    fused_back<<<1728, 256, 0, stream>>>(xcatH, fragTabW, bf, asppH,
                                         coords, cells, scanEx, chunkTot,
                                         lrank, qidx, qdata);
    decoder_mlp_mfma<<<4608, 1024, 0, stream>>>(asppH, qidx, qdata, fragTab,
                                                mb0, mb1, mw2, mb2, out);
}